// Round 12
// baseline (359.210 us; speedup 1.0000x reference)
//
#include <hip/hip_runtime.h>

typedef unsigned short u16;
typedef __attribute__((ext_vector_type(8))) short bf16x8;
typedef __attribute__((ext_vector_type(4))) float f32x4;

struct __align__(8) U16x4 { u16 a, b, c, d; };

__device__ __forceinline__ u16 f2bf(float f) {
  union { float f; unsigned int u; } cv; cv.f = f;
  unsigned int u = cv.u;
  unsigned int r = (u + 0x7fffu + ((u >> 16) & 1u)) >> 16;  // RNE
  return (u16)r;
}

__device__ __forceinline__ void gld16(const u16* g, u16* l) {
  __builtin_amdgcn_global_load_lds((const __attribute__((address_space(1))) void*)g,
                                   (__attribute__((address_space(3))) void*)l, 16, 0, 0);
}

// ---------------------------------------------------------------------------
// conv: fp32 x -> bf16 xbf, same layout. grid*2048 elems.
// (Kept separate: fusing into gemm_k<1> reg-staging cost +56 us — R2.)
// ---------------------------------------------------------------------------
__global__ void conv_k(const float* __restrict__ x, u16* __restrict__ xbf) {
  size_t i = ((size_t)blockIdx.x * 256 + threadIdx.x) * 8;
  u16 tmp[8];
  #pragma unroll
  for (int j = 0; j < 8; j++) tmp[j] = f2bf(x[i + j]);
  *(bf16x8*)&xbf[i] = *(const bf16x8*)&tmp[0];
}

// ---------------------------------------------------------------------------
// Prep: fp32 weights -> bf16 transposed weights.
// ---------------------------------------------------------------------------
__global__ void prep_k(const float* __restrict__ Wq, const float* __restrict__ Wkv,
                       const float* __restrict__ Wo, u16* __restrict__ WT1,
                       u16* __restrict__ WoT) {
  int idx = blockIdx.x * 256 + threadIdx.x;
  if (idx < 1536 * 256) {
    int c = idx >> 8, k = idx & 255;
    WT1[idx] = (c < 512) ? f2bf(Wq[(size_t)k * 512 + c])
                         : f2bf(Wkv[(size_t)k * 1024 + (c - 512)]);
  }
  if (idx < 256 * 512) {
    int nn = idx >> 9, kk = idx & 511;
    WoT[idx] = f2bf(Wo[(size_t)kk * 256 + nn]);
  }
}

// ---------------------------------------------------------------------------
// GEMM core: 128x128 tiles, mfma 16x16x32 bf16, 256 threads (2x2 waves).
// K-loop: double-buffer prefetch + COUNTED vmcnt (T4). Each step issues
// next-kb's 4 global_load_lds into buf[cur^1], waits s_waitcnt vmcnt(4)
// (own cur-loads done; new 4 stay in flight ACROSS both barriers), RAW
// s_barrier, MFMA on buf[cur], WAR s_barrier. Tail waits vmcnt(0).
// FENCING (R10 post-mortem): raw s_barrier has NO memory semantics at IR
// level — R10 lacked a fence AFTER the WAR barrier, so the compiler
// hoisted the next iteration's STAGE (LDS writes into the buffer being
// read) above it -> race, absmax 0.084. Every raw barrier must have
// asm memory clobber + sched_barrier(0) on BOTH sides.
// NOTE: staging is a MACRO, not a lambda — device lambdas capturing
// LDS pointers fail to compile on gfx950 (addrspacecast static init, R8).
// __launch_bounds__(256,4): (256,5) spilled acc (R5: VGPR 48, 2x slower).
// KIND 1: QKV   (bf16 out; V cols transposed-scatter via LDS)
//         n-fast + XCD-chunked bid map (x fetched from HBM ~once).
// KIND 2: dots  (fp32 out, split-K, tied (r,d) gather)
// KIND 3: PV    (bf16 out)
// KIND 4: proj  (fp32 out + bias)
// ---------------------------------------------------------------------------
template<int KIND>
__global__ void __launch_bounds__(256, 4) gemm_k(
    const u16* __restrict__ A, const u16* __restrict__ B,
    u16* __restrict__ C, u16* __restrict__ C2,
    float* __restrict__ SF, const float* __restrict__ bias,
    int aux0, int nk32) {
  __shared__ __align__(16) u16 lsm[16384];   // 32 KB

  const int tid  = threadIdx.x;
  const int bid  = blockIdx.x;
  const int lane = tid & 63;
  const int wv   = tid >> 6;
  const int l15  = lane & 15;
  const int quad = lane >> 4;
  const int mq   = (wv & 1) * 64;
  const int nq   = (wv >> 1) * 64;

  int m0, n0, NK2, kb0 = 0;
  int s = 0, p = 0;
  if constexpr (KIND == 1) {
    // n-fast, XCD-chunked. grid = mt*12, mt in {256,512} -> grid % 8 == 0.
    int nwg = aux0 * 12;
    int per = nwg >> 3;
    int sw  = (bid & 7) * per + (bid >> 3);  // contiguous sw range per XCD
    m0 = (sw / 12) * 128; n0 = (sw % 12) * 128; NK2 = 4;
  } else if constexpr (KIND == 2) {
    int npS = aux0;                            // 3 or 4 (np = 8 or 16)
    n0 = (bid & 3) * 128; m0 = ((bid >> 2) & 3) * 128;
    p = (bid >> 4) & ((1 << npS) - 1); s = bid >> (4 + npS);
    NK2 = nk32 >> 1; kb0 = s * nk32;
  } else if constexpr (KIND == 3) {
    n0 = (bid & 31) * 128; m0 = ((bid >> 5) & 3) * 128; p = bid >> 7; NK2 = 8;
  } else {
    n0 = (bid & 1) * 128; m0 = (bid >> 1) * 128; NK2 = 8;
  }

  f32x4 acc[4][4];
  #pragma unroll
  for (int i = 0; i < 4; i++)
    #pragma unroll
    for (int j = 0; j < 4; j++)
      #pragma unroll
      for (int g = 0; g < 4; g++) acc[i][j][g] = 0.f;

  const int ar0 = tid >> 2;       // staging row (0..63); +64 second chunk
  const int ac0 = (tid & 3) * 8;  // staging col (elems)

// Stage one BK=32 sub-tile (kb_) into LDS buffer bi_ (0/1).
#define STAGE_KB(kb_, bi_)                                                     \
  do {                                                                         \
    const int kb = (kb_);                                                      \
    size_t aBase, bBase; int aRS, bRS;                                         \
    if constexpr (KIND == 1) {                                                 \
      aBase = (size_t)m0 * 256 + kb * 32; aRS = 256;                           \
      bBase = (size_t)n0 * 256 + kb * 32; bRS = 256;                           \
    } else if constexpr (KIND == 2) {                                          \
      int bt = p >> 3, hl = p & 7;                                             \
      int r = kb >> 1, dlo = (kb & 1) * 32;                                    \
      size_t rowblk = (size_t)bt * 32768 + (size_t)r * 512;                    \
      aBase = (rowblk + m0) * 1024 + hl * 64 + dlo;        aRS = 1024;         \
      bBase = (rowblk + n0) * 1024 + 512 + hl * 64 + dlo;  bRS = 1024;         \
    } else if constexpr (KIND == 3) {                                          \
      aBase = ((size_t)p * 512 + m0) * 512 + kb * 32;   aRS = 512;             \
      bBase = ((size_t)p * 4096 + n0) * 512 + kb * 32;  bRS = 512;             \
    } else {                                                                   \
      int bt = m0 >> 15, h = kb >> 1, dlo = (kb & 1) * 32;                     \
      aBase = ((size_t)(bt * 8 + h) * 512 + (m0 & 511)) * 4096                 \
              + ((m0 >> 9) & 63) * 64 + dlo;                                   \
      aRS = 4096;                                                              \
      bBase = (size_t)n0 * 512 + kb * 32; bRS = 512;                           \
    }                                                                          \
    u16* lA_ = lsm + (bi_) * 4096;                                             \
    u16* lB_ = lsm + 8192 + (bi_) * 4096;                                      \
    gld16(A + aBase + (size_t)ar0 * aRS + ac0,        &lA_[tid * 8]);          \
    gld16(A + aBase + (size_t)(ar0 + 64) * aRS + ac0, &lA_[(tid + 256) * 8]);  \
    gld16(B + bBase + (size_t)ar0 * bRS + ac0,        &lB_[tid * 8]);          \
    gld16(B + bBase + (size_t)(ar0 + 64) * bRS + ac0, &lB_[(tid + 256) * 8]);  \
  } while (0)

  const int NKtot = NK2 * 2;
  STAGE_KB(kb0, 0);

  for (int step = 0; step < NKtot; ++step) {
    const int cur = step & 1;
    if (step + 1 < NKtot) {
      STAGE_KB(kb0 + step + 1, cur ^ 1);               // 4 new loads in flight
      asm volatile("s_waitcnt vmcnt(4)" ::: "memory"); // own cur-loads done
    } else {
      asm volatile("s_waitcnt vmcnt(0)" ::: "memory"); // tail: drain all
    }
    __builtin_amdgcn_sched_barrier(0);
    __builtin_amdgcn_s_barrier();                      // RAW: all waves' cur ready
    __builtin_amdgcn_sched_barrier(0);
    asm volatile("" ::: "memory");

    const u16* lA = lsm + cur * 4096;
    const u16* lB = lsm + 8192 + cur * 4096;
    bf16x8 af[4], bfr[4];
    #pragma unroll
    for (int mi = 0; mi < 4; mi++)
      af[mi] = *(const bf16x8*)&lA[(mq + mi * 16 + l15) * 32 + quad * 8];
    #pragma unroll
    for (int ni = 0; ni < 4; ni++)
      bfr[ni] = *(const bf16x8*)&lB[(nq + ni * 16 + l15) * 32 + quad * 8];
    #pragma unroll
    for (int mi = 0; mi < 4; mi++)
      #pragma unroll
      for (int ni = 0; ni < 4; ni++)
        acc[mi][ni] = __builtin_amdgcn_mfma_f32_16x16x32_bf16(af[mi], bfr[ni], acc[mi][ni], 0, 0, 0);

    asm volatile("" ::: "memory");
    __builtin_amdgcn_sched_barrier(0);
    __builtin_amdgcn_s_barrier();                      // WAR: cur fully read
    __builtin_amdgcn_sched_barrier(0);
    asm volatile("" ::: "memory");                     // R10 bug: this fence
                                                       // was missing -> stage
                                                       // hoisted above barrier
  }
#undef STAGE_KB

  // ----- Epilogues (C/D frag: col = lane&15, row = quad*4 + reg) -----------
  if constexpr (KIND == 1 || KIND == 3) {
    if (KIND == 3 || n0 < 1024) {
      // bf16 row-major out: 2 passes x 64 rows, LDS stride 136
      #pragma unroll
      for (int ps = 0; ps < 2; ps++) {
        if ((mq >> 6) == ps) {
          #pragma unroll
          for (int mi = 0; mi < 4; mi++)
            #pragma unroll
            for (int ni = 0; ni < 4; ni++) {
              int lr = mi * 16 + quad * 4;
              int lc = nq + ni * 16 + l15;
              #pragma unroll
              for (int g = 0; g < 4; g++)
                lsm[(lr + g) * 136 + lc] = f2bf(acc[mi][ni][g]);
            }
        }
        __syncthreads();
        #pragma unroll
        for (int it = 0; it < 4; it++) {
          int idx = tid + it * 256;
          int lr = idx >> 4, c = (idx & 15) * 8;
          int gm = m0 + ps * 64 + lr;
          size_t gaddr;
          if constexpr (KIND == 1) gaddr = (size_t)gm * 1024 + n0 + c;
          else                     gaddr = ((size_t)p * 512 + gm) * 4096 + n0 + c;
          *(bf16x8*)&C[gaddr] = *(const bf16x8*)&lsm[lr * 136 + c];
        }
        __syncthreads();
      }
    } else {
      // V transposed out: stage [n_local][j]; rows become j-contiguous
      #pragma unroll
      for (int ps = 0; ps < 2; ps++) {
        if ((nq >> 6) == ps) {
          #pragma unroll
          for (int mi = 0; mi < 4; mi++)
            #pragma unroll
            for (int ni = 0; ni < 4; ni++) {
              int lrn = ni * 16 + l15;
              int lcm = mq + mi * 16 + quad * 4;
              U16x4 pk;
              pk.a = f2bf(acc[mi][ni][0]); pk.b = f2bf(acc[mi][ni][1]);
              pk.c = f2bf(acc[mi][ni][2]); pk.d = f2bf(acc[mi][ni][3]);
              *(U16x4*)&lsm[lrn * 136 + lcm] = pk;
            }
        }
        __syncthreads();
        int bt2 = m0 >> 15;
        int r  = (m0 >> 9) & 63;
        int jb = (m0 & 511);
        #pragma unroll
        for (int it = 0; it < 4; it++) {
          int idx = tid + it * 256;
          int lr = idx >> 4, c = (idx & 15) * 8;
          int cc = (n0 - 1024) + ps * 64 + lr;
          int h = cc >> 6, d = cc & 63;
          size_t gaddr = ((size_t)(bt2 * 8 + h) * 4096 + r * 64 + d) * 512 + jb + c;
          *(bf16x8*)&C2[gaddr] = *(const bf16x8*)&lsm[lr * 136 + c];
        }
        __syncthreads();
      }
    }
  } else {
    // fp32 out: 4 passes x 32 rows, LDS stride 132 floats
    float* lsf = (float*)lsm;
    #pragma unroll
    for (int ps = 0; ps < 4; ps++) {
      if ((mq >> 6) == (ps >> 1)) {
        int miA = (ps & 1) * 2;
        #pragma unroll
        for (int mm = 0; mm < 2; mm++) {
          int mi = miA + mm;
          #pragma unroll
          for (int ni = 0; ni < 4; ni++) {
            int lr = mm * 16 + quad * 4;
            int lc = nq + ni * 16 + l15;
            #pragma unroll
            for (int g = 0; g < 4; g++)
              lsf[(lr + g) * 132 + lc] = acc[mi][ni][g];
          }
        }
      }
      __syncthreads();
      #pragma unroll
      for (int it = 0; it < 4; it++) {
        int idx = tid + it * 256;
        int lr = idx >> 5, c = (idx & 31) * 4;
        int gm = m0 + ps * 32 + lr;
        f32x4 v = *(const f32x4*)&lsf[lr * 132 + c];
        if constexpr (KIND == 2) {
          int npS = aux0;
          *(f32x4*)&SF[((size_t)((s << npS) + p) * 512 + gm) * 512 + n0 + c] = v;
        } else {
          f32x4 bo4 = *(const f32x4*)&bias[n0 + c];
          v[0] += bo4[0]; v[1] += bo4[1]; v[2] += bo4[2]; v[3] += bo4[3];
          *(f32x4*)&SF[(size_t)gm * 256 + n0 + c] = v;
        }
      }
      __syncthreads();
    }
  }
}

// ---------------------------------------------------------------------------
// Softmax over j, fp32: sums split-K partials, scale = 1/64, emits bf16 P.
// grid = np*512 blocks; np passed for split stride. float2 loads, packed
// u32 store (thread t owns cols 2t, 2t+1).
// ---------------------------------------------------------------------------
__global__ void softmax_k(const float* __restrict__ SP, u16* __restrict__ P,
                          int nsplit, int np) {
  int bid = blockIdx.x;
  int p = bid >> 9, i = bid & 511;
  int t = threadIdx.x;
  size_t rowbase = ((size_t)p * 512 + i) * 512;
  float v0 = 0.f, v1 = 0.f;
  for (int ss = 0; ss < nsplit; ss++) {
    size_t off = (size_t)ss * np * 512 * 512;
    float2 u = *(const float2*)&SP[off + rowbase + 2 * t];
    v0 += u.x; v1 += u.y;
  }
  const float scale = 1.0f / 64.0f;
  v0 *= scale; v1 *= scale;

  int wv = t >> 6, ln = t & 63;
  float m = fmaxf(v0, v1);
  for (int o = 32; o > 0; o >>= 1) m = fmaxf(m, __shfl_down(m, o));
  __shared__ float sred[4];
  if (ln == 0) sred[wv] = m;
  __syncthreads();
  m = fmaxf(fmaxf(sred[0], sred[1]), fmaxf(sred[2], sred[3]));

  float e0 = expf(v0 - m), e1 = expf(v1 - m);
  float sum = e0 + e1;
  for (int o = 32; o > 0; o >>= 1) sum += __shfl_down(sum, o);
  __shared__ float sred2[4];
  if (ln == 0) sred2[wv] = sum;
  __syncthreads();
  float inv = 1.0f / (sred2[0] + sred2[1] + sred2[2] + sred2[3]);

  unsigned int pk = (unsigned int)f2bf(e0 * inv)
                  | ((unsigned int)f2bf(e1 * inv) << 16);
  *(unsigned int*)&P[rowbase + 2 * t] = pk;
}

// ---------------------------------------------------------------------------
// fp32 in / fp32 out; internal bf16. If ws_size permits the whole problem
// runs in single launches (np=16); else two sequential halves (np=8).
// xbf aliases the SP split-K region (disjoint lifetimes). OT aliases QK.
// ---------------------------------------------------------------------------
extern "C" void kernel_launch(void* const* d_in, const int* in_sizes, int n_in,
                              void* d_out, int out_size, void* d_ws, size_t ws_size,
                              hipStream_t stream) {
  (void)in_sizes; (void)n_in; (void)out_size;
  const float* x   = (const float*)d_in[0];
  const float* Wq  = (const float*)d_in[1];
  const float* Wkv = (const float*)d_in[2];
  const float* Wo  = (const float*)d_in[3];
  const float* bo  = (const float*)d_in[4];
  float* out = (float*)d_out;

  const size_t MB = 1024ull * 1024ull;
  // Decide mode from ws_size (host-constant => graph-capture stable).
  const int ns_m = 2;                       // split-K depth (SP = ns*16 MB)
  bool merged = (ws_size >= 235 * MB);
  // merged footprint: 1 + 128 + 64 + 8 + max(32, ns*16) MB (+ slack)

  char* ws = (char*)d_ws;
  size_t off = 0;
  u16* WT1 = (u16*)(ws + off); off += (size_t)1536 * 256 * 2;
  u16* WoT = (u16*)(ws + off); off += (size_t)256 * 512 * 2;

  prep_k<<<dim3(1536), dim3(256), 0, stream>>>(Wq, Wkv, Wo, WT1, WoT);

  if (merged) {
    const int np = 16, npS = 4, ns = ns_m;
    u16* QK = (u16*)(ws + off); off += (size_t)65536 * 1024 * 2;     // 128 MB
    u16* OT = QK;                                                    // alias
    u16* VT = (u16*)(ws + off); off += (size_t)np * 4096 * 512 * 2;  //  64 MB
    u16* Pb = (u16*)(ws + off); off += (size_t)np * 512 * 512 * 2;   //   8 MB
    char* XS = ws + off;
    u16* xbf = (u16*)XS;   // 64 MB, aliases SP (disjoint lifetimes)
    float* SP = (float*)XS;

    conv_k<<<dim3(8192), dim3(256), 0, stream>>>(x, xbf);
    gemm_k<1><<<dim3(512 * 12), dim3(256), 0, stream>>>(xbf, WT1, QK, VT,
                                                        nullptr, nullptr, 512, 0);
    gemm_k<2><<<dim3(ns * np * 16), dim3(256), 0, stream>>>(QK, QK, nullptr, nullptr,
                                                            SP, nullptr, npS, 128 / ns);
    softmax_k<<<dim3(np * 512), dim3(256), 0, stream>>>(SP, Pb, ns, np);
    gemm_k<3><<<dim3(np * 128), dim3(256), 0, stream>>>(Pb, VT, OT, nullptr,
                                                        nullptr, nullptr, 0, 0);
    gemm_k<4><<<dim3(1024), dim3(256), 0, stream>>>(OT, WoT, nullptr, nullptr,
                                                    out, bo, 0, 0);
  } else {
    const int np = 8, npS = 3;
    u16* QKb = (u16*)(ws + off); off += (size_t)32768 * 1024 * 2;    //  64 MB
    u16* OTb = QKb;                                                  // alias
    u16* VTb = (u16*)(ws + off); off += (size_t)np * 4096 * 512 * 2; //  32 MB
    u16* Pb  = (u16*)(ws + off); off += (size_t)np * 512 * 512 * 2;  //   4 MB
    char* XS = ws + off;
    u16* xbf = (u16*)XS;
    float* SPb = (float*)XS;
    size_t rem = (ws_size > off) ? (ws_size - off) : 0;
    int ns = 2;
    while (ns > 1 && (size_t)ns * np * 512 * 512 * 4 > rem) ns >>= 1;

    for (int bt = 0; bt < 2; bt++) {
      const float* xb = x + (size_t)bt * 32768 * 256;
      float* outb = out + (size_t)bt * 32768 * 256;
      conv_k<<<dim3(4096), dim3(256), 0, stream>>>(xb, xbf);
      gemm_k<1><<<dim3(256 * 12), dim3(256), 0, stream>>>(xbf, WT1, QKb, VTb,
                                                          nullptr, nullptr, 256, 0);
      gemm_k<2><<<dim3(ns * np * 16), dim3(256), 0, stream>>>(QKb, QKb, nullptr, nullptr,
                                                              SPb, nullptr, npS, 128 / ns);
      softmax_k<<<dim3(np * 512), dim3(256), 0, stream>>>(SPb, Pb, ns, np);
      gemm_k<3><<<dim3(np * 128), dim3(256), 0, stream>>>(Pb, VTb, OTb, nullptr,
                                                          nullptr, nullptr, 0, 0);
      gemm_k<4><<<dim3(512), dim3(256), 0, stream>>>(OTb, WoT, nullptr, nullptr,
                                                     outb, bo, 0, 0);
    }
  }
}

// Round 13
// 333.972 us; speedup vs baseline: 1.0756x; 1.0756x over previous
//
#include <hip/hip_runtime.h>

typedef unsigned short u16;
typedef __attribute__((ext_vector_type(8))) short bf16x8;
typedef __attribute__((ext_vector_type(4))) float f32x4;

struct __align__(8) U16x4 { u16 a, b, c, d; };

__device__ __forceinline__ u16 f2bf(float f) {
  union { float f; unsigned int u; } cv; cv.f = f;
  unsigned int u = cv.u;
  unsigned int r = (u + 0x7fffu + ((u >> 16) & 1u)) >> 16;  // RNE
  return (u16)r;
}

__device__ __forceinline__ void gld16(const u16* g, u16* l) {
  __builtin_amdgcn_global_load_lds((const __attribute__((address_space(1))) void*)g,
                                   (__attribute__((address_space(3))) void*)l, 16, 0, 0);
}

// ---------------------------------------------------------------------------
// conv: fp32 x -> bf16 xbf, same layout. grid*2048 elems.
// (Kept separate: fusing into gemm_k<1> reg-staging cost +56 us — R2.)
// ---------------------------------------------------------------------------
__global__ void conv_k(const float* __restrict__ x, u16* __restrict__ xbf) {
  size_t i = ((size_t)blockIdx.x * 256 + threadIdx.x) * 8;
  u16 tmp[8];
  #pragma unroll
  for (int j = 0; j < 8; j++) tmp[j] = f2bf(x[i + j]);
  *(bf16x8*)&xbf[i] = *(const bf16x8*)&tmp[0];
}

// ---------------------------------------------------------------------------
// Prep: fp32 weights -> bf16 transposed weights.
// ---------------------------------------------------------------------------
__global__ void prep_k(const float* __restrict__ Wq, const float* __restrict__ Wkv,
                       const float* __restrict__ Wo, u16* __restrict__ WT1,
                       u16* __restrict__ WoT) {
  int idx = blockIdx.x * 256 + threadIdx.x;
  if (idx < 1536 * 256) {
    int c = idx >> 8, k = idx & 255;
    WT1[idx] = (c < 512) ? f2bf(Wq[(size_t)k * 512 + c])
                         : f2bf(Wkv[(size_t)k * 1024 + (c - 512)]);
  }
  if (idx < 256 * 512) {
    int nn = idx >> 9, kk = idx & 511;
    WoT[idx] = f2bf(Wo[(size_t)kk * 256 + nn]);
  }
}

// ---------------------------------------------------------------------------
// GEMM core: 128x128 tiles, mfma 16x16x32 bf16, 256 threads (2x2 waves).
// K-loop: double-buffer prefetch + counted vmcnt(4) with full fencing
// (R10 race fixed in R12; verified passing, perf-neutral vs __syncthreads
// — kept because it is the verified state).
// XCD-CHUNKED bid MAP ON ALL KINDS (R12 analysis): blocks sharing an
// L2-sized input slice must land on the SAME XCD. Raw round-robin bid
// scattered each 16-block (s,p) group of KIND 2 across all 8 XCDs ->
// 8x redundant HBM fetch (g2 FETCH 197MB vs ~80 ideal). Same transform
// as KIND 1 (which cut g1 FETCH 164->20MB in R1): sw = (bid&7)*per +
// (bid>>3), decode tile coords from sw. Grids all divisible by 8.
// NOTE: staging is a MACRO, not a lambda (gfx950 addrspacecast bug, R8).
// __launch_bounds__(256,4): (256,5) spilled acc (R5).
// KIND 1: QKV   (bf16 out; V cols transposed-scatter via LDS)
// KIND 2: dots  (fp32 out, split-K, tied (r,d) gather); aux0=npS
// KIND 3: PV    (bf16 out); aux0=np
// KIND 4: proj  (fp32 out + bias); aux0=grid size
// ---------------------------------------------------------------------------
template<int KIND>
__global__ void __launch_bounds__(256, 4) gemm_k(
    const u16* __restrict__ A, const u16* __restrict__ B,
    u16* __restrict__ C, u16* __restrict__ C2,
    float* __restrict__ SF, const float* __restrict__ bias,
    int aux0, int nk32) {
  __shared__ __align__(16) u16 lsm[16384];   // 32 KB

  const int tid  = threadIdx.x;
  const int bid  = blockIdx.x;
  const int lane = tid & 63;
  const int wv   = tid >> 6;
  const int l15  = lane & 15;
  const int quad = lane >> 4;
  const int mq   = (wv & 1) * 64;
  const int nq   = (wv >> 1) * 64;

  int m0, n0, NK2, kb0 = 0;
  int s = 0, p = 0;
  if constexpr (KIND == 1) {
    int nwg = aux0 * 12;
    int per = nwg >> 3;
    int sw  = (bid & 7) * per + (bid >> 3);
    m0 = (sw / 12) * 128; n0 = (sw % 12) * 128; NK2 = 4;
  } else if constexpr (KIND == 2) {
    int npS = aux0;                            // 3 or 4 (np = 8 or 16)
    int nblk = (128 / nk32) << (npS + 4);      // ns * np * 16
    int per = nblk >> 3;
    int sw  = (bid & 7) * per + (bid >> 3);    // (s,p) 16-block groups stay
    n0 = (sw & 3) * 128; m0 = ((sw >> 2) & 3) * 128;   // on one XCD
    p = (sw >> 4) & ((1 << npS) - 1); s = sw >> (4 + npS);
    NK2 = nk32 >> 1; kb0 = s * nk32;
  } else if constexpr (KIND == 3) {
    int nblk = aux0 * 128;                     // np * 128
    int per = nblk >> 3;
    int sw  = (bid & 7) * per + (bid >> 3);    // p-groups (128 blocks) stay
    n0 = (sw & 31) * 128; m0 = ((sw >> 5) & 3) * 128; p = sw >> 7; NK2 = 8;
  } else {
    int per = aux0 >> 3;                       // aux0 = grid size
    int sw  = (bid & 7) * per + (bid >> 3);    // (n0=0,1) pairs share A rows
    n0 = (sw & 1) * 128; m0 = (sw >> 1) * 128; NK2 = 8;
  }

  f32x4 acc[4][4];
  #pragma unroll
  for (int i = 0; i < 4; i++)
    #pragma unroll
    for (int j = 0; j < 4; j++)
      #pragma unroll
      for (int g = 0; g < 4; g++) acc[i][j][g] = 0.f;

  const int ar0 = tid >> 2;       // staging row (0..63); +64 second chunk
  const int ac0 = (tid & 3) * 8;  // staging col (elems)

// Stage one BK=32 sub-tile (kb_) into LDS buffer bi_ (0/1).
#define STAGE_KB(kb_, bi_)                                                     \
  do {                                                                         \
    const int kb = (kb_);                                                      \
    size_t aBase, bBase; int aRS, bRS;                                         \
    if constexpr (KIND == 1) {                                                 \
      aBase = (size_t)m0 * 256 + kb * 32; aRS = 256;                           \
      bBase = (size_t)n0 * 256 + kb * 32; bRS = 256;                           \
    } else if constexpr (KIND == 2) {                                          \
      int bt = p >> 3, hl = p & 7;                                             \
      int r = kb >> 1, dlo = (kb & 1) * 32;                                    \
      size_t rowblk = (size_t)bt * 32768 + (size_t)r * 512;                    \
      aBase = (rowblk + m0) * 1024 + hl * 64 + dlo;        aRS = 1024;         \
      bBase = (rowblk + n0) * 1024 + 512 + hl * 64 + dlo;  bRS = 1024;         \
    } else if constexpr (KIND == 3) {                                          \
      aBase = ((size_t)p * 512 + m0) * 512 + kb * 32;   aRS = 512;             \
      bBase = ((size_t)p * 4096 + n0) * 512 + kb * 32;  bRS = 512;             \
    } else {                                                                   \
      int bt = m0 >> 15, h = kb >> 1, dlo = (kb & 1) * 32;                     \
      aBase = ((size_t)(bt * 8 + h) * 512 + (m0 & 511)) * 4096                 \
              + ((m0 >> 9) & 63) * 64 + dlo;                                   \
      aRS = 4096;                                                              \
      bBase = (size_t)n0 * 512 + kb * 32; bRS = 512;                           \
    }                                                                          \
    u16* lA_ = lsm + (bi_) * 4096;                                             \
    u16* lB_ = lsm + 8192 + (bi_) * 4096;                                      \
    gld16(A + aBase + (size_t)ar0 * aRS + ac0,        &lA_[tid * 8]);          \
    gld16(A + aBase + (size_t)(ar0 + 64) * aRS + ac0, &lA_[(tid + 256) * 8]);  \
    gld16(B + bBase + (size_t)ar0 * bRS + ac0,        &lB_[tid * 8]);          \
    gld16(B + bBase + (size_t)(ar0 + 64) * bRS + ac0, &lB_[(tid + 256) * 8]);  \
  } while (0)

  const int NKtot = NK2 * 2;
  STAGE_KB(kb0, 0);

  for (int step = 0; step < NKtot; ++step) {
    const int cur = step & 1;
    if (step + 1 < NKtot) {
      STAGE_KB(kb0 + step + 1, cur ^ 1);               // 4 new loads in flight
      asm volatile("s_waitcnt vmcnt(4)" ::: "memory"); // own cur-loads done
    } else {
      asm volatile("s_waitcnt vmcnt(0)" ::: "memory"); // tail: drain all
    }
    __builtin_amdgcn_sched_barrier(0);
    __builtin_amdgcn_s_barrier();                      // RAW: all waves' cur ready
    __builtin_amdgcn_sched_barrier(0);
    asm volatile("" ::: "memory");

    const u16* lA = lsm + cur * 4096;
    const u16* lB = lsm + 8192 + cur * 4096;
    bf16x8 af[4], bfr[4];
    #pragma unroll
    for (int mi = 0; mi < 4; mi++)
      af[mi] = *(const bf16x8*)&lA[(mq + mi * 16 + l15) * 32 + quad * 8];
    #pragma unroll
    for (int ni = 0; ni < 4; ni++)
      bfr[ni] = *(const bf16x8*)&lB[(nq + ni * 16 + l15) * 32 + quad * 8];
    #pragma unroll
    for (int mi = 0; mi < 4; mi++)
      #pragma unroll
      for (int ni = 0; ni < 4; ni++)
        acc[mi][ni] = __builtin_amdgcn_mfma_f32_16x16x32_bf16(af[mi], bfr[ni], acc[mi][ni], 0, 0, 0);

    asm volatile("" ::: "memory");
    __builtin_amdgcn_sched_barrier(0);
    __builtin_amdgcn_s_barrier();                      // WAR: cur fully read
    __builtin_amdgcn_sched_barrier(0);
    asm volatile("" ::: "memory");                     // post-fence: R10 bug fix
  }
#undef STAGE_KB

  // ----- Epilogues (C/D frag: col = lane&15, row = quad*4 + reg) -----------
  if constexpr (KIND == 1 || KIND == 3) {
    if (KIND == 3 || n0 < 1024) {
      // bf16 row-major out: 2 passes x 64 rows, LDS stride 136
      #pragma unroll
      for (int ps = 0; ps < 2; ps++) {
        if ((mq >> 6) == ps) {
          #pragma unroll
          for (int mi = 0; mi < 4; mi++)
            #pragma unroll
            for (int ni = 0; ni < 4; ni++) {
              int lr = mi * 16 + quad * 4;
              int lc = nq + ni * 16 + l15;
              #pragma unroll
              for (int g = 0; g < 4; g++)
                lsm[(lr + g) * 136 + lc] = f2bf(acc[mi][ni][g]);
            }
        }
        __syncthreads();
        #pragma unroll
        for (int it = 0; it < 4; it++) {
          int idx = tid + it * 256;
          int lr = idx >> 4, c = (idx & 15) * 8;
          int gm = m0 + ps * 64 + lr;
          size_t gaddr;
          if constexpr (KIND == 1) gaddr = (size_t)gm * 1024 + n0 + c;
          else                     gaddr = ((size_t)p * 512 + gm) * 4096 + n0 + c;
          *(bf16x8*)&C[gaddr] = *(const bf16x8*)&lsm[lr * 136 + c];
        }
        __syncthreads();
      }
    } else {
      // V transposed out: stage [n_local][j]; rows become j-contiguous
      #pragma unroll
      for (int ps = 0; ps < 2; ps++) {
        if ((nq >> 6) == ps) {
          #pragma unroll
          for (int mi = 0; mi < 4; mi++)
            #pragma unroll
            for (int ni = 0; ni < 4; ni++) {
              int lrn = ni * 16 + l15;
              int lcm = mq + mi * 16 + quad * 4;
              U16x4 pk;
              pk.a = f2bf(acc[mi][ni][0]); pk.b = f2bf(acc[mi][ni][1]);
              pk.c = f2bf(acc[mi][ni][2]); pk.d = f2bf(acc[mi][ni][3]);
              *(U16x4*)&lsm[lrn * 136 + lcm] = pk;
            }
        }
        __syncthreads();
        int bt2 = m0 >> 15;
        int r  = (m0 >> 9) & 63;
        int jb = (m0 & 511);
        #pragma unroll
        for (int it = 0; it < 4; it++) {
          int idx = tid + it * 256;
          int lr = idx >> 4, c = (idx & 15) * 8;
          int cc = (n0 - 1024) + ps * 64 + lr;
          int h = cc >> 6, d = cc & 63;
          size_t gaddr = ((size_t)(bt2 * 8 + h) * 4096 + r * 64 + d) * 512 + jb + c;
          *(bf16x8*)&C2[gaddr] = *(const bf16x8*)&lsm[lr * 136 + c];
        }
        __syncthreads();
      }
    }
  } else {
    // fp32 out: 4 passes x 32 rows, LDS stride 132 floats
    float* lsf = (float*)lsm;
    #pragma unroll
    for (int ps = 0; ps < 4; ps++) {
      if ((mq >> 6) == (ps >> 1)) {
        int miA = (ps & 1) * 2;
        #pragma unroll
        for (int mm = 0; mm < 2; mm++) {
          int mi = miA + mm;
          #pragma unroll
          for (int ni = 0; ni < 4; ni++) {
            int lr = mm * 16 + quad * 4;
            int lc = nq + ni * 16 + l15;
            #pragma unroll
            for (int g = 0; g < 4; g++)
              lsf[(lr + g) * 132 + lc] = acc[mi][ni][g];
          }
        }
      }
      __syncthreads();
      #pragma unroll
      for (int it = 0; it < 4; it++) {
        int idx = tid + it * 256;
        int lr = idx >> 5, c = (idx & 31) * 4;
        int gm = m0 + ps * 32 + lr;
        f32x4 v = *(const f32x4*)&lsf[lr * 132 + c];
        if constexpr (KIND == 2) {
          int npS = aux0;
          *(f32x4*)&SF[((size_t)((s << npS) + p) * 512 + gm) * 512 + n0 + c] = v;
        } else {
          f32x4 bo4 = *(const f32x4*)&bias[n0 + c];
          v[0] += bo4[0]; v[1] += bo4[1]; v[2] += bo4[2]; v[3] += bo4[3];
          *(f32x4*)&SF[(size_t)gm * 256 + n0 + c] = v;
        }
      }
      __syncthreads();
    }
  }
}

// ---------------------------------------------------------------------------
// Softmax over j, fp32: sums split-K partials, scale = 1/64, emits bf16 P.
// grid = np*512 blocks; np passed for split stride. float2 loads, packed
// u32 store (thread t owns cols 2t, 2t+1).
// ---------------------------------------------------------------------------
__global__ void softmax_k(const float* __restrict__ SP, u16* __restrict__ P,
                          int nsplit, int np) {
  int bid = blockIdx.x;
  int p = bid >> 9, i = bid & 511;
  int t = threadIdx.x;
  size_t rowbase = ((size_t)p * 512 + i) * 512;
  float v0 = 0.f, v1 = 0.f;
  for (int ss = 0; ss < nsplit; ss++) {
    size_t off = (size_t)ss * np * 512 * 512;
    float2 u = *(const float2*)&SP[off + rowbase + 2 * t];
    v0 += u.x; v1 += u.y;
  }
  const float scale = 1.0f / 64.0f;
  v0 *= scale; v1 *= scale;

  int wv = t >> 6, ln = t & 63;
  float m = fmaxf(v0, v1);
  for (int o = 32; o > 0; o >>= 1) m = fmaxf(m, __shfl_down(m, o));
  __shared__ float sred[4];
  if (ln == 0) sred[wv] = m;
  __syncthreads();
  m = fmaxf(fmaxf(sred[0], sred[1]), fmaxf(sred[2], sred[3]));

  float e0 = expf(v0 - m), e1 = expf(v1 - m);
  float sum = e0 + e1;
  for (int o = 32; o > 0; o >>= 1) sum += __shfl_down(sum, o);
  __shared__ float sred2[4];
  if (ln == 0) sred2[wv] = sum;
  __syncthreads();
  float inv = 1.0f / (sred2[0] + sred2[1] + sred2[2] + sred2[3]);

  unsigned int pk = (unsigned int)f2bf(e0 * inv)
                  | ((unsigned int)f2bf(e1 * inv) << 16);
  *(unsigned int*)&P[rowbase + 2 * t] = pk;
}

// ---------------------------------------------------------------------------
// fp32 in / fp32 out; internal bf16. If ws_size permits the whole problem
// runs in single launches (np=16); else two sequential halves (np=8).
// xbf aliases the SP split-K region (disjoint lifetimes). OT aliases QK.
// ---------------------------------------------------------------------------
extern "C" void kernel_launch(void* const* d_in, const int* in_sizes, int n_in,
                              void* d_out, int out_size, void* d_ws, size_t ws_size,
                              hipStream_t stream) {
  (void)in_sizes; (void)n_in; (void)out_size;
  const float* x   = (const float*)d_in[0];
  const float* Wq  = (const float*)d_in[1];
  const float* Wkv = (const float*)d_in[2];
  const float* Wo  = (const float*)d_in[3];
  const float* bo  = (const float*)d_in[4];
  float* out = (float*)d_out;

  const size_t MB = 1024ull * 1024ull;
  // Decide mode from ws_size (host-constant => graph-capture stable).
  const int ns_m = 2;                       // split-K depth (SP = ns*16 MB)
  bool merged = (ws_size >= 235 * MB);
  // merged footprint: 1 + 128 + 64 + 8 + max(32, ns*16) MB (+ slack)

  char* ws = (char*)d_ws;
  size_t off = 0;
  u16* WT1 = (u16*)(ws + off); off += (size_t)1536 * 256 * 2;
  u16* WoT = (u16*)(ws + off); off += (size_t)256 * 512 * 2;

  prep_k<<<dim3(1536), dim3(256), 0, stream>>>(Wq, Wkv, Wo, WT1, WoT);

  if (merged) {
    const int np = 16, npS = 4, ns = ns_m;
    u16* QK = (u16*)(ws + off); off += (size_t)65536 * 1024 * 2;     // 128 MB
    u16* OT = QK;                                                    // alias
    u16* VT = (u16*)(ws + off); off += (size_t)np * 4096 * 512 * 2;  //  64 MB
    u16* Pb = (u16*)(ws + off); off += (size_t)np * 512 * 512 * 2;   //   8 MB
    char* XS = ws + off;
    u16* xbf = (u16*)XS;   // 64 MB, aliases SP (disjoint lifetimes)
    float* SP = (float*)XS;

    conv_k<<<dim3(8192), dim3(256), 0, stream>>>(x, xbf);
    gemm_k<1><<<dim3(512 * 12), dim3(256), 0, stream>>>(xbf, WT1, QK, VT,
                                                        nullptr, nullptr, 512, 0);
    gemm_k<2><<<dim3(ns * np * 16), dim3(256), 0, stream>>>(QK, QK, nullptr, nullptr,
                                                            SP, nullptr, npS, 128 / ns);
    softmax_k<<<dim3(np * 512), dim3(256), 0, stream>>>(SP, Pb, ns, np);
    gemm_k<3><<<dim3(np * 128), dim3(256), 0, stream>>>(Pb, VT, OT, nullptr,
                                                        nullptr, nullptr, np, 0);
    gemm_k<4><<<dim3(1024), dim3(256), 0, stream>>>(OT, WoT, nullptr, nullptr,
                                                    out, bo, 1024, 0);
  } else {
    const int np = 8, npS = 3;
    u16* QKb = (u16*)(ws + off); off += (size_t)32768 * 1024 * 2;    //  64 MB
    u16* OTb = QKb;                                                  // alias
    u16* VTb = (u16*)(ws + off); off += (size_t)np * 4096 * 512 * 2; //  32 MB
    u16* Pb  = (u16*)(ws + off); off += (size_t)np * 512 * 512 * 2;  //   4 MB
    char* XS = ws + off;
    u16* xbf = (u16*)XS;
    float* SPb = (float*)XS;
    size_t rem = (ws_size > off) ? (ws_size - off) : 0;
    int ns = 2;
    while (ns > 1 && (size_t)ns * np * 512 * 512 * 4 > rem) ns >>= 1;

    for (int bt = 0; bt < 2; bt++) {
      const float* xb = x + (size_t)bt * 32768 * 256;
      float* outb = out + (size_t)bt * 32768 * 256;
      conv_k<<<dim3(4096), dim3(256), 0, stream>>>(xb, xbf);
      gemm_k<1><<<dim3(256 * 12), dim3(256), 0, stream>>>(xbf, WT1, QKb, VTb,
                                                          nullptr, nullptr, 256, 0);
      gemm_k<2><<<dim3(ns * np * 16), dim3(256), 0, stream>>>(QKb, QKb, nullptr, nullptr,
                                                              SPb, nullptr, npS, 128 / ns);
      softmax_k<<<dim3(np * 512), dim3(256), 0, stream>>>(SPb, Pb, ns, np);
      gemm_k<3><<<dim3(np * 128), dim3(256), 0, stream>>>(Pb, VTb, OTb, nullptr,
                                                          nullptr, nullptr, np, 0);
      gemm_k<4><<<dim3(512), dim3(256), 0, stream>>>(OTb, WoT, nullptr, nullptr,
                                                     outb, bo, 512, 0);
    }
  }
}

// Round 14
// 330.476 us; speedup vs baseline: 1.0869x; 1.0106x over previous
//
#include <hip/hip_runtime.h>

typedef unsigned short u16;
typedef __attribute__((ext_vector_type(8))) short bf16x8;
typedef __attribute__((ext_vector_type(4))) float f32x4;

struct __align__(8) U16x4 { u16 a, b, c, d; };

__device__ __forceinline__ u16 f2bf(float f) {
  union { float f; unsigned int u; } cv; cv.f = f;
  unsigned int u = cv.u;
  unsigned int r = (u + 0x7fffu + ((u >> 16) & 1u)) >> 16;  // RNE
  return (u16)r;
}

__device__ __forceinline__ void gld16(const u16* g, u16* l) {
  __builtin_amdgcn_global_load_lds((const __attribute__((address_space(1))) void*)g,
                                   (__attribute__((address_space(3))) void*)l, 16, 0, 0);
}

// ---------------------------------------------------------------------------
// conv: fp32 x -> bf16 xbf, same layout. grid*2048 elems.
// (Kept separate: fusing into gemm_k<1> reg-staging cost +56 us — R2.)
// ---------------------------------------------------------------------------
__global__ void conv_k(const float* __restrict__ x, u16* __restrict__ xbf) {
  size_t i = ((size_t)blockIdx.x * 256 + threadIdx.x) * 8;
  u16 tmp[8];
  #pragma unroll
  for (int j = 0; j < 8; j++) tmp[j] = f2bf(x[i + j]);
  *(bf16x8*)&xbf[i] = *(const bf16x8*)&tmp[0];
}

// ---------------------------------------------------------------------------
// Prep: fp32 weights -> bf16 transposed weights.
// ---------------------------------------------------------------------------
__global__ void prep_k(const float* __restrict__ Wq, const float* __restrict__ Wkv,
                       const float* __restrict__ Wo, u16* __restrict__ WT1,
                       u16* __restrict__ WoT) {
  int idx = blockIdx.x * 256 + threadIdx.x;
  if (idx < 1536 * 256) {
    int c = idx >> 8, k = idx & 255;
    WT1[idx] = (c < 512) ? f2bf(Wq[(size_t)k * 512 + c])
                         : f2bf(Wkv[(size_t)k * 1024 + (c - 512)]);
  }
  if (idx < 256 * 512) {
    int nn = idx >> 9, kk = idx & 511;
    WoT[idx] = f2bf(Wo[(size_t)kk * 256 + nn]);
  }
}

// ---------------------------------------------------------------------------
// GEMM core: 128x128 tiles, mfma 16x16x32 bf16, 256 threads (2x2 waves).
// K-loop (R14): 3-SLOT LDS ROTATION, ONE fenced barrier per BK=32 step
// (was 2 with the 2-buffer scheme — irreducible there because WAR-barrier
// -> stage -> vmcnt -> RAW-barrier forms a cycle). With 3 slots, at
// barrier_s the slot (s+2)%3 was last read at step s-1, so the single
// barrier is simultaneously RAW for slot s%3 and WAR for slot (s+2)%3:
//   vmcnt(4) [kb_s done; kb_{s+1}'s 4 stay in flight across the barrier]
//   FENCED barrier
//   stage(kb_{s+2} -> slot (s+2)%3)
//   compute(slot s%3)
// vmcnt(0) only at the final step. R13's 2-phase structure capped every
// GEMM at ~25% MfmaUtil / 33% HBM (m233 stage+barrier overhead); halving
// barrier count attacks that directly. LDS 48 KB -> 3 blocks/CU
// (occupancy 4->3 was ~neutral historically: R4 era).
// POST-LOOP __syncthreads REQUIRED: last step has no trailing barrier;
// epilogue reuses lsm while other waves may still be reading slots.
// FENCING: every raw s_barrier gets asm memory clobber + sched_barrier(0)
// on BOTH sides (R10 post-mortem: missing post-fence -> stage hoisted
// above barrier -> race).
// NOTE: staging is a MACRO, not a lambda (gfx950 addrspacecast bug, R8).
// XCD-chunked bid map on all KINDs (R13: g2 FETCH 197->~80 MB).
// KIND 1: QKV   (bf16 out; V cols transposed-scatter via LDS)
// KIND 2: dots  (fp32 out, split-K, tied (r,d) gather); aux0=npS
// KIND 3: PV    (bf16 out); aux0=np
// KIND 4: proj  (fp32 out + bias); aux0=grid size
// ---------------------------------------------------------------------------
template<int KIND>
__global__ void __launch_bounds__(256, 3) gemm_k(
    const u16* __restrict__ A, const u16* __restrict__ B,
    u16* __restrict__ C, u16* __restrict__ C2,
    float* __restrict__ SF, const float* __restrict__ bias,
    int aux0, int nk32) {
  __shared__ __align__(16) u16 lsm[24576];   // 48 KB: 3 A-slots + 3 B-slots

  const int tid  = threadIdx.x;
  const int bid  = blockIdx.x;
  const int lane = tid & 63;
  const int wv   = tid >> 6;
  const int l15  = lane & 15;
  const int quad = lane >> 4;
  const int mq   = (wv & 1) * 64;
  const int nq   = (wv >> 1) * 64;

  int m0, n0, NK2, kb0 = 0;
  int s = 0, p = 0;
  if constexpr (KIND == 1) {
    int nwg = aux0 * 12;
    int per = nwg >> 3;
    int sw  = (bid & 7) * per + (bid >> 3);
    m0 = (sw / 12) * 128; n0 = (sw % 12) * 128; NK2 = 4;
  } else if constexpr (KIND == 2) {
    int npS = aux0;                            // 3 or 4 (np = 8 or 16)
    int nblk = (128 / nk32) << (npS + 4);      // ns * np * 16
    int per = nblk >> 3;
    int sw  = (bid & 7) * per + (bid >> 3);
    n0 = (sw & 3) * 128; m0 = ((sw >> 2) & 3) * 128;
    p = (sw >> 4) & ((1 << npS) - 1); s = sw >> (4 + npS);
    NK2 = nk32 >> 1; kb0 = s * nk32;
  } else if constexpr (KIND == 3) {
    int nblk = aux0 * 128;                     // np * 128
    int per = nblk >> 3;
    int sw  = (bid & 7) * per + (bid >> 3);
    n0 = (sw & 31) * 128; m0 = ((sw >> 5) & 3) * 128; p = sw >> 7; NK2 = 8;
  } else {
    int per = aux0 >> 3;                       // aux0 = grid size
    int sw  = (bid & 7) * per + (bid >> 3);
    n0 = (sw & 1) * 128; m0 = (sw >> 1) * 128; NK2 = 8;
  }

  f32x4 acc[4][4];
  #pragma unroll
  for (int i = 0; i < 4; i++)
    #pragma unroll
    for (int j = 0; j < 4; j++)
      #pragma unroll
      for (int g = 0; g < 4; g++) acc[i][j][g] = 0.f;

  const int ar0 = tid >> 2;       // staging row (0..63); +64 second chunk
  const int ac0 = (tid & 3) * 8;  // staging col (elems)

// Stage one BK=32 sub-tile (kb_) into LDS slot si_ (0/1/2).
#define STAGE_KB(kb_, si_)                                                     \
  do {                                                                         \
    const int kb = (kb_);                                                      \
    size_t aBase, bBase; int aRS, bRS;                                         \
    if constexpr (KIND == 1) {                                                 \
      aBase = (size_t)m0 * 256 + kb * 32; aRS = 256;                           \
      bBase = (size_t)n0 * 256 + kb * 32; bRS = 256;                           \
    } else if constexpr (KIND == 2) {                                          \
      int bt = p >> 3, hl = p & 7;                                             \
      int r = kb >> 1, dlo = (kb & 1) * 32;                                    \
      size_t rowblk = (size_t)bt * 32768 + (size_t)r * 512;                    \
      aBase = (rowblk + m0) * 1024 + hl * 64 + dlo;        aRS = 1024;         \
      bBase = (rowblk + n0) * 1024 + 512 + hl * 64 + dlo;  bRS = 1024;         \
    } else if constexpr (KIND == 3) {                                          \
      aBase = ((size_t)p * 512 + m0) * 512 + kb * 32;   aRS = 512;             \
      bBase = ((size_t)p * 4096 + n0) * 512 + kb * 32;  bRS = 512;             \
    } else {                                                                   \
      int bt = m0 >> 15, h = kb >> 1, dlo = (kb & 1) * 32;                     \
      aBase = ((size_t)(bt * 8 + h) * 512 + (m0 & 511)) * 4096                 \
              + ((m0 >> 9) & 63) * 64 + dlo;                                   \
      aRS = 4096;                                                              \
      bBase = (size_t)n0 * 512 + kb * 32; bRS = 512;                           \
    }                                                                          \
    u16* lA_ = lsm + (si_) * 4096;                                             \
    u16* lB_ = lsm + 12288 + (si_) * 4096;                                     \
    gld16(A + aBase + (size_t)ar0 * aRS + ac0,        &lA_[tid * 8]);          \
    gld16(A + aBase + (size_t)(ar0 + 64) * aRS + ac0, &lA_[(tid + 256) * 8]);  \
    gld16(B + bBase + (size_t)ar0 * bRS + ac0,        &lB_[tid * 8]);          \
    gld16(B + bBase + (size_t)(ar0 + 64) * bRS + ac0, &lB_[(tid + 256) * 8]);  \
  } while (0)

  const int NKtot = NK2 * 2;
  STAGE_KB(kb0, 0);
  STAGE_KB(kb0 + 1, 1);

  for (int step = 0; step < NKtot; ++step) {
    const int sl = step % 3;
    if (step + 1 < NKtot) {
      asm volatile("s_waitcnt vmcnt(4)" ::: "memory"); // kb_step done; next 4 fly
    } else {
      asm volatile("s_waitcnt vmcnt(0)" ::: "memory"); // final step: drain
    }
    __builtin_amdgcn_sched_barrier(0);
    __builtin_amdgcn_s_barrier();   // RAW(slot sl) + WAR(slot (step+2)%3)
    __builtin_amdgcn_sched_barrier(0);
    asm volatile("" ::: "memory");

    if (step + 2 < NKtot) STAGE_KB(kb0 + step + 2, (step + 2) % 3);

    const u16* lA = lsm + sl * 4096;
    const u16* lB = lsm + 12288 + sl * 4096;
    bf16x8 af[4], bfr[4];
    #pragma unroll
    for (int mi = 0; mi < 4; mi++)
      af[mi] = *(const bf16x8*)&lA[(mq + mi * 16 + l15) * 32 + quad * 8];
    #pragma unroll
    for (int ni = 0; ni < 4; ni++)
      bfr[ni] = *(const bf16x8*)&lB[(nq + ni * 16 + l15) * 32 + quad * 8];
    #pragma unroll
    for (int mi = 0; mi < 4; mi++)
      #pragma unroll
      for (int ni = 0; ni < 4; ni++)
        acc[mi][ni] = __builtin_amdgcn_mfma_f32_16x16x32_bf16(af[mi], bfr[ni], acc[mi][ni], 0, 0, 0);

    asm volatile("" ::: "memory");
    __builtin_amdgcn_sched_barrier(0);
  }
#undef STAGE_KB

  __syncthreads();  // REQUIRED: no trailing loop barrier; epilogue reuses lsm

  // ----- Epilogues (C/D frag: col = lane&15, row = quad*4 + reg) -----------
  if constexpr (KIND == 1 || KIND == 3) {
    if (KIND == 3 || n0 < 1024) {
      // bf16 row-major out: 2 passes x 64 rows, LDS stride 136
      #pragma unroll
      for (int ps = 0; ps < 2; ps++) {
        if ((mq >> 6) == ps) {
          #pragma unroll
          for (int mi = 0; mi < 4; mi++)
            #pragma unroll
            for (int ni = 0; ni < 4; ni++) {
              int lr = mi * 16 + quad * 4;
              int lc = nq + ni * 16 + l15;
              #pragma unroll
              for (int g = 0; g < 4; g++)
                lsm[(lr + g) * 136 + lc] = f2bf(acc[mi][ni][g]);
            }
        }
        __syncthreads();
        #pragma unroll
        for (int it = 0; it < 4; it++) {
          int idx = tid + it * 256;
          int lr = idx >> 4, c = (idx & 15) * 8;
          int gm = m0 + ps * 64 + lr;
          size_t gaddr;
          if constexpr (KIND == 1) gaddr = (size_t)gm * 1024 + n0 + c;
          else                     gaddr = ((size_t)p * 512 + gm) * 4096 + n0 + c;
          *(bf16x8*)&C[gaddr] = *(const bf16x8*)&lsm[lr * 136 + c];
        }
        __syncthreads();
      }
    } else {
      // V transposed out: stage [n_local][j]; rows become j-contiguous
      #pragma unroll
      for (int ps = 0; ps < 2; ps++) {
        if ((nq >> 6) == ps) {
          #pragma unroll
          for (int mi = 0; mi < 4; mi++)
            #pragma unroll
            for (int ni = 0; ni < 4; ni++) {
              int lrn = ni * 16 + l15;
              int lcm = mq + mi * 16 + quad * 4;
              U16x4 pk;
              pk.a = f2bf(acc[mi][ni][0]); pk.b = f2bf(acc[mi][ni][1]);
              pk.c = f2bf(acc[mi][ni][2]); pk.d = f2bf(acc[mi][ni][3]);
              *(U16x4*)&lsm[lrn * 136 + lcm] = pk;
            }
        }
        __syncthreads();
        int bt2 = m0 >> 15;
        int r  = (m0 >> 9) & 63;
        int jb = (m0 & 511);
        #pragma unroll
        for (int it = 0; it < 4; it++) {
          int idx = tid + it * 256;
          int lr = idx >> 4, c = (idx & 15) * 8;
          int cc = (n0 - 1024) + ps * 64 + lr;
          int h = cc >> 6, d = cc & 63;
          size_t gaddr = ((size_t)(bt2 * 8 + h) * 4096 + r * 64 + d) * 512 + jb + c;
          *(bf16x8*)&C2[gaddr] = *(const bf16x8*)&lsm[lr * 136 + c];
        }
        __syncthreads();
      }
    }
  } else {
    // fp32 out: 4 passes x 32 rows, LDS stride 132 floats
    float* lsf = (float*)lsm;
    #pragma unroll
    for (int ps = 0; ps < 4; ps++) {
      if ((mq >> 6) == (ps >> 1)) {
        int miA = (ps & 1) * 2;
        #pragma unroll
        for (int mm = 0; mm < 2; mm++) {
          int mi = miA + mm;
          #pragma unroll
          for (int ni = 0; ni < 4; ni++) {
            int lr = mm * 16 + quad * 4;
            int lc = nq + ni * 16 + l15;
            #pragma unroll
            for (int g = 0; g < 4; g++)
              lsf[(lr + g) * 132 + lc] = acc[mi][ni][g];
          }
        }
      }
      __syncthreads();
      #pragma unroll
      for (int it = 0; it < 4; it++) {
        int idx = tid + it * 256;
        int lr = idx >> 5, c = (idx & 31) * 4;
        int gm = m0 + ps * 32 + lr;
        f32x4 v = *(const f32x4*)&lsf[lr * 132 + c];
        if constexpr (KIND == 2) {
          int npS = aux0;
          *(f32x4*)&SF[((size_t)((s << npS) + p) * 512 + gm) * 512 + n0 + c] = v;
        } else {
          f32x4 bo4 = *(const f32x4*)&bias[n0 + c];
          v[0] += bo4[0]; v[1] += bo4[1]; v[2] += bo4[2]; v[3] += bo4[3];
          *(f32x4*)&SF[(size_t)gm * 256 + n0 + c] = v;
        }
      }
      __syncthreads();
    }
  }
}

// ---------------------------------------------------------------------------
// Softmax over j, fp32: sums split-K partials, scale = 1/64, emits bf16 P.
// grid = np*512 blocks; np passed for split stride. float2 loads, packed
// u32 store (thread t owns cols 2t, 2t+1).
// ---------------------------------------------------------------------------
__global__ void softmax_k(const float* __restrict__ SP, u16* __restrict__ P,
                          int nsplit, int np) {
  int bid = blockIdx.x;
  int p = bid >> 9, i = bid & 511;
  int t = threadIdx.x;
  size_t rowbase = ((size_t)p * 512 + i) * 512;
  float v0 = 0.f, v1 = 0.f;
  for (int ss = 0; ss < nsplit; ss++) {
    size_t off = (size_t)ss * np * 512 * 512;
    float2 u = *(const float2*)&SP[off + rowbase + 2 * t];
    v0 += u.x; v1 += u.y;
  }
  const float scale = 1.0f / 64.0f;
  v0 *= scale; v1 *= scale;

  int wv = t >> 6, ln = t & 63;
  float m = fmaxf(v0, v1);
  for (int o = 32; o > 0; o >>= 1) m = fmaxf(m, __shfl_down(m, o));
  __shared__ float sred[4];
  if (ln == 0) sred[wv] = m;
  __syncthreads();
  m = fmaxf(fmaxf(sred[0], sred[1]), fmaxf(sred[2], sred[3]));

  float e0 = expf(v0 - m), e1 = expf(v1 - m);
  float sum = e0 + e1;
  for (int o = 32; o > 0; o >>= 1) sum += __shfl_down(sum, o);
  __shared__ float sred2[4];
  if (ln == 0) sred2[wv] = sum;
  __syncthreads();
  float inv = 1.0f / (sred2[0] + sred2[1] + sred2[2] + sred2[3]);

  unsigned int pk = (unsigned int)f2bf(e0 * inv)
                  | ((unsigned int)f2bf(e1 * inv) << 16);
  *(unsigned int*)&P[rowbase + 2 * t] = pk;
}

// ---------------------------------------------------------------------------
// fp32 in / fp32 out; internal bf16. If ws_size permits the whole problem
// runs in single launches (np=16); else two sequential halves (np=8).
// xbf aliases the SP split-K region (disjoint lifetimes). OT aliases QK.
// ---------------------------------------------------------------------------
extern "C" void kernel_launch(void* const* d_in, const int* in_sizes, int n_in,
                              void* d_out, int out_size, void* d_ws, size_t ws_size,
                              hipStream_t stream) {
  (void)in_sizes; (void)n_in; (void)out_size;
  const float* x   = (const float*)d_in[0];
  const float* Wq  = (const float*)d_in[1];
  const float* Wkv = (const float*)d_in[2];
  const float* Wo  = (const float*)d_in[3];
  const float* bo  = (const float*)d_in[4];
  float* out = (float*)d_out;

  const size_t MB = 1024ull * 1024ull;
  // Decide mode from ws_size (host-constant => graph-capture stable).
  const int ns_m = 2;                       // split-K depth
  bool merged = (ws_size >= 235 * MB);

  char* ws = (char*)d_ws;
  size_t off = 0;
  u16* WT1 = (u16*)(ws + off); off += (size_t)1536 * 256 * 2;
  u16* WoT = (u16*)(ws + off); off += (size_t)256 * 512 * 2;

  prep_k<<<dim3(1536), dim3(256), 0, stream>>>(Wq, Wkv, Wo, WT1, WoT);

  if (merged) {
    const int np = 16, npS = 4, ns = ns_m;
    u16* QK = (u16*)(ws + off); off += (size_t)65536 * 1024 * 2;     // 128 MB
    u16* OT = QK;                                                    // alias
    u16* VT = (u16*)(ws + off); off += (size_t)np * 4096 * 512 * 2;  //  64 MB
    u16* Pb = (u16*)(ws + off); off += (size_t)np * 512 * 512 * 2;   //   8 MB
    char* XS = ws + off;
    u16* xbf = (u16*)XS;   // 64 MB, aliases SP (disjoint lifetimes)
    float* SP = (float*)XS;

    conv_k<<<dim3(8192), dim3(256), 0, stream>>>(x, xbf);
    gemm_k<1><<<dim3(512 * 12), dim3(256), 0, stream>>>(xbf, WT1, QK, VT,
                                                        nullptr, nullptr, 512, 0);
    gemm_k<2><<<dim3(ns * np * 16), dim3(256), 0, stream>>>(QK, QK, nullptr, nullptr,
                                                            SP, nullptr, npS, 128 / ns);
    softmax_k<<<dim3(np * 512), dim3(256), 0, stream>>>(SP, Pb, ns, np);
    gemm_k<3><<<dim3(np * 128), dim3(256), 0, stream>>>(Pb, VT, OT, nullptr,
                                                        nullptr, nullptr, np, 0);
    gemm_k<4><<<dim3(1024), dim3(256), 0, stream>>>(OT, WoT, nullptr, nullptr,
                                                    out, bo, 1024, 0);
  } else {
    const int np = 8, npS = 3;
    u16* QKb = (u16*)(ws + off); off += (size_t)32768 * 1024 * 2;    //  64 MB
    u16* OTb = QKb;                                                  // alias
    u16* VTb = (u16*)(ws + off); off += (size_t)np * 4096 * 512 * 2; //  32 MB
    u16* Pb  = (u16*)(ws + off); off += (size_t)np * 512 * 512 * 2;  //   4 MB
    char* XS = ws + off;
    u16* xbf = (u16*)XS;
    float* SPb = (float*)XS;
    size_t rem = (ws_size > off) ? (ws_size - off) : 0;
    int ns = 2;
    while (ns > 1 && (size_t)ns * np * 512 * 512 * 4 > rem) ns >>= 1;

    for (int bt = 0; bt < 2; bt++) {
      const float* xb = x + (size_t)bt * 32768 * 256;
      float* outb = out + (size_t)bt * 32768 * 256;
      conv_k<<<dim3(4096), dim3(256), 0, stream>>>(xb, xbf);
      gemm_k<1><<<dim3(256 * 12), dim3(256), 0, stream>>>(xbf, WT1, QKb, VTb,
                                                          nullptr, nullptr, 256, 0);
      gemm_k<2><<<dim3(ns * np * 16), dim3(256), 0, stream>>>(QKb, QKb, nullptr, nullptr,
                                                              SPb, nullptr, npS, 128 / ns);
      softmax_k<<<dim3(np * 512), dim3(256), 0, stream>>>(SPb, Pb, ns, np);
      gemm_k<3><<<dim3(np * 128), dim3(256), 0, stream>>>(Pb, VTb, OTb, nullptr,
                                                          nullptr, nullptr, np, 0);
      gemm_k<4><<<dim3(512), dim3(256), 0, stream>>>(OTb, WoT, nullptr, nullptr,
                                                     outb, bo, 512, 0);
    }
  }
}